// Round 12
// baseline (259.979 us; speedup 1.0000x reference)
//
#include <hip/hip_runtime.h>
#include <math.h>

typedef unsigned short u16;
typedef unsigned int u32;

#define N_ROWS 8192
#define DDIM 512
#define HDIM 1024
#define ODIM 512
#define NEXP 8
#define MAXPAIRS (N_ROWS * 2)          // 16384
#define MAXPOS (MAXPAIRS + NEXP * 128) // 17408 (per-expert segments 128-aligned)
#define MAXTILES (MAXPOS / 128)        // 136

// small-region word indices (in d_ws)
#define SM_CNT 0   // (unused since R19 partials)
#define SM_CUR 8   // 8 ints: scatter cursors
#define SM_AOFF 16 // 9 ints: aligned bucket offsets
#define SM_WORDS 64

using short8 = __attribute__((ext_vector_type(8))) short;
using float4v = __attribute__((ext_vector_type(4))) float;

__device__ __forceinline__ u16 f2bf(float f) {
    union { float f; u32 u; } v; v.f = f;
    u32 u = v.u;
    return (u16)((u + 0x7fffu + ((u >> 16) & 1u)) >> 16);
}

// async global->LDS, 16B per lane; HW places lane i at lds_base + i*16
__device__ __forceinline__ void async_copy16(u16* lds, const u16* g) {
    __builtin_amdgcn_global_load_lds(
        (const __attribute__((address_space(1))) void*)g,
        (__attribute__((address_space(3))) void*)lds, 16, 0, 0);
}

// ---------------- mega: gate + W1/W2 convert + owT + bucket/small/zeropage init ----------------
// R19-proven: gate is LDS-free, writes DENSE per-block partials.
#define MEGA_GATE 512   // N_ROWS/16
#define MEGA_W1 2048    // 2 float4/thread
#define MEGA_OWT 256
#define MEGA_BUCKET 68
#define MEGA_W2 2048    // 2 float4/thread
#define MEGA_BLOCKS (MEGA_GATE + MEGA_W1 + MEGA_OWT + MEGA_BUCKET + MEGA_W2) // 4932
__global__ __launch_bounds__(256) void mega_kernel(
    const float* __restrict__ x, const float* __restrict__ noise,
    const float* __restrict__ norm_w, const float* __restrict__ norm_b,
    const float* __restrict__ w_gate, const float* __restrict__ w_noise,
    const float* __restrict__ W1, const float* __restrict__ ow,
    const float* __restrict__ W2,
    u16* __restrict__ xnorm_bf, u16* __restrict__ x_bf,
    int* __restrict__ pair_expert, float* __restrict__ pair_gate,
    u16* __restrict__ W1b, u16* __restrict__ owT, u16* __restrict__ W2b,
    int* __restrict__ bucket_rows, int* __restrict__ small, float* __restrict__ zeropage,
    float* __restrict__ partial_g, float* __restrict__ partial_l, int* __restrict__ partial_c)
{
    __shared__ __align__(16) float sh[32 * 33 + 8];
    int b = blockIdx.x, tid = threadIdx.x;

    if (b >= MEGA_GATE) {
        int cb = b - MEGA_GATE;
        if (cb < MEGA_W1) { // W1 fp32->bf16, 2 float4/thread
            size_t i = (size_t)cb * 512 + tid;
#pragma unroll
            for (int t = 0; t < 2; t++, i += 256) {
                float4 v = ((const float4*)W1)[i];
                ushort4 o;
                o.x = f2bf(v.x); o.y = f2bf(v.y); o.z = f2bf(v.z); o.w = f2bf(v.w);
                ((ushort4*)W1b)[i] = o;
            }
        } else if (cb < MEGA_W1 + MEGA_OWT) { // ow transpose -> owT bf16
            float (*tile)[33] = (float(*)[33])sh;
            int t = cb - MEGA_W1;
            int bx = (t & 15) * 32, by = (t >> 4) * 32;
            int tx = tid & 31, ty = tid >> 5; // 32 x 8
            for (int r = ty; r < 32; r += 8) tile[r][tx] = ow[(size_t)(by + r) * ODIM + bx + tx];
            __syncthreads();
            for (int r = ty; r < 32; r += 8) owT[(size_t)(bx + r) * DDIM + by + tx] = f2bf(tile[tx][r]);
        } else if (cb < MEGA_W1 + MEGA_OWT + MEGA_BUCKET) { // bucket init (+small/zeropage in block 0)
            int lb = cb - MEGA_W1 - MEGA_OWT;
            int i = lb * 256 + tid;
            if (i < MAXPOS) bucket_rows[i] = -1;
            if (lb == 0) {
                if (tid < SM_WORDS) small[tid] = 0;
                zeropage[tid] = 0.f; zeropage[tid + 256] = 0.f;
            }
        } else { // W2 fp32->bf16, 2 float4/thread
            int j = cb - MEGA_W1 - MEGA_OWT - MEGA_BUCKET;
            size_t i = (size_t)j * 512 + tid;
#pragma unroll
            for (int t = 0; t < 2; t++, i += 256) {
                float4 v = ((const float4*)W2)[i];
                ushort4 o;
                o.x = f2bf(v.x); o.y = f2bf(v.y); o.z = f2bf(v.z); o.w = f2bf(v.w);
                ((ushort4*)W2b)[i] = o;
            }
        }
        return;
    }

    // ---- gate path: 16 rows/block, LDS-free weights, partials out ----
    float* lg = sh;                  // [16][17]
    float* blk_g = sh + 16 * 17;     // [8]
    float* blk_l = blk_g + 8;        // [8]
    int* blk_c = (int*)(blk_l + 8);  // [8]

    int wave = tid >> 6, lane = tid & 63;
    if (tid < 8) { blk_g[tid] = 0.f; blk_l[tid] = 0.f; blk_c[tid] = 0; }
    float nw[8], nb[8];
#pragma unroll
    for (int j = 0; j < 8; j++) { nw[j] = norm_w[j * 64 + lane]; nb[j] = norm_b[j * 64 + lane]; }

    bool l5 = (lane & 32) != 0, l4 = (lane & 16) != 0;
    bool l3 = (lane & 8) != 0, l2 = (lane & 4) != 0;

    for (int half = 0; half < 2; ++half) { // 2 rows at a time keeps VGPR ~100
        float xv[2][8], mu[2], rstd[2];
#pragma unroll
        for (int r = 0; r < 2; ++r) {
            int row = b * 16 + wave * 4 + half * 2 + r;
            const float* xr = x + (size_t)row * DDIM;
            float s = 0.f, s2 = 0.f;
#pragma unroll
            for (int j = 0; j < 8; j++) { float v = xr[j * 64 + lane]; xv[r][j] = v; s += v; s2 += v * v; }
#pragma unroll
            for (int o = 32; o; o >>= 1) { s += __shfl_xor(s, o, 64); s2 += __shfl_xor(s2, o, 64); }
            mu[r] = s * (1.f / DDIM);
            float var = s2 * (1.f / DDIM) - mu[r] * mu[r];
            rstd[r] = rsqrtf(var + 1e-6f);
        }
        float acc[2][16];
#pragma unroll
        for (int r = 0; r < 2; ++r)
#pragma unroll
            for (int e = 0; e < 16; e++) acc[r][e] = 0.f;
#pragma unroll
        for (int j = 0; j < 8; j++) {
            int d = j * 64 + lane;
            float4 wg0 = *(const float4*)&w_gate[d * 8];
            float4 wg1 = *(const float4*)&w_gate[d * 8 + 4];
            float4 wn0 = *(const float4*)&w_noise[d * 8];
            float4 wn1 = *(const float4*)&w_noise[d * 8 + 4];
#pragma unroll
            for (int r = 0; r < 2; ++r) {
                int row = b * 16 + wave * 4 + half * 2 + r;
                float v = (xv[r][j] - mu[r]) * rstd[r] * nw[j] + nb[j];
                xnorm_bf[(size_t)row * DDIM + d] = f2bf(v);
                x_bf[(size_t)row * DDIM + d] = f2bf(xv[r][j]);
                acc[r][0] += v * wg0.x; acc[r][1] += v * wg0.y;
                acc[r][2] += v * wg0.z; acc[r][3] += v * wg0.w;
                acc[r][4] += v * wg1.x; acc[r][5] += v * wg1.y;
                acc[r][6] += v * wg1.z; acc[r][7] += v * wg1.w;
                acc[r][8] += v * wn0.x; acc[r][9] += v * wn0.y;
                acc[r][10] += v * wn0.z; acc[r][11] += v * wn0.w;
                acc[r][12] += v * wn1.x; acc[r][13] += v * wn1.y;
                acc[r][14] += v * wn1.z; acc[r][15] += v * wn1.w;
            }
        }
        // value-split butterfly (R9-proven): lane l ends with full sum of value (l>>2)&15
#pragma unroll
        for (int r = 0; r < 2; ++r) {
            int lrow16 = wave * 4 + half * 2 + r;
            float t8[8];
#pragma unroll
            for (int v = 0; v < 8; v++) {
                float snd = l5 ? acc[r][v] : acc[r][v + 8];
                float kp = l5 ? acc[r][v + 8] : acc[r][v];
                t8[v] = kp + __shfl_xor(snd, 32, 64);
            }
            float t4[4];
#pragma unroll
            for (int v = 0; v < 4; v++) {
                float snd = l4 ? t8[v] : t8[v + 4];
                float kp = l4 ? t8[v + 4] : t8[v];
                t4[v] = kp + __shfl_xor(snd, 16, 64);
            }
            float t2[2];
#pragma unroll
            for (int v = 0; v < 2; v++) {
                float snd = l3 ? t4[v] : t4[v + 2];
                float kp = l3 ? t4[v + 2] : t4[v];
                t2[v] = kp + __shfl_xor(snd, 8, 64);
            }
            float snd = l2 ? t2[0] : t2[1];
            float kp = l2 ? t2[1] : t2[0];
            float t1 = kp + __shfl_xor(snd, 4, 64);
            t1 += __shfl_xor(t1, 2, 64);
            t1 += __shfl_xor(t1, 1, 64);
            if ((lane & 3) == 0) lg[lrow16 * 17 + ((lane >> 2) & 15)] = t1;
        }
    }
    __syncthreads();

    if (tid < 16) { // one lane per row: softplus + noisy + top3 + erf
        int row = b * 16 + tid;
        float cl[8], sd[8], nz[8];
#pragma unroll
        for (int e = 0; e < 8; e++) {
            cl[e] = lg[tid * 17 + e];
            float t = lg[tid * 17 + 8 + e];
            float sp = fmaxf(t, 0.f) + log1pf(expf(-fabsf(t))); // stable softplus
            sd[e] = sp + 0.01f;
            nz[e] = cl[e] + noise[(size_t)row * NEXP + e] * sd[e];
        }
        // top-3 (strict > = lowest-index tie-break, matching lax.top_k)
        int idx[3]; float val[3]; u32 msk = 0;
#pragma unroll
        for (int t = 0; t < 3; t++) {
            float best = -INFINITY; int bi = 0;
#pragma unroll
            for (int e = 0; e < 8; e++)
                if (!((msk >> e) & 1) && nz[e] > best) { best = nz[e]; bi = e; }
            idx[t] = bi; val[t] = best; msk |= 1u << bi;
        }
        float e1 = expf(val[1] - val[0]);
        float g0 = 1.f / (1.f + e1), g1 = e1 / (1.f + e1);
        float thr_in = val[2], thr_out = val[1];

        pair_expert[row * 2] = idx[0]; pair_gate[row * 2] = g0;
        pair_expert[row * 2 + 1] = idx[1]; pair_gate[row * 2 + 1] = g1;
        atomicAdd(&blk_g[idx[0]], g0); atomicAdd(&blk_g[idx[1]], g1);
        atomicAdd(&blk_c[idx[0]], 1); atomicAdd(&blk_c[idx[1]], 1);
#pragma unroll
        for (int e = 0; e < 8; e++) {
            float thr = (nz[e] > thr_in) ? thr_in : thr_out;
            float z = (cl[e] - thr) / sd[e];
            float p = 0.5f * (1.f + erff(z * 0.70710678118654752f));
            atomicAdd(&blk_l[e], p);
        }
    }
    __syncthreads();
    if (tid < 8) { // dense partials: fully overwritten, no init needed
        partial_g[b * 8 + tid] = blk_g[tid];
        partial_l[b * 8 + tid] = blk_l[tid];
        partial_c[b * 8 + tid] = blk_c[tid];
    }
}

// ---------------- scatter: partial reduce + prefix + loss/load + scatter + rowpos ----------------
__global__ __launch_bounds__(256) void scatter_kernel(
    const int* __restrict__ pair_expert, const float* __restrict__ pair_gate,
    const float* __restrict__ partial_g, const float* __restrict__ partial_l,
    const int* __restrict__ partial_c,
    int* __restrict__ small, int* __restrict__ bucket_rows, float* __restrict__ gate_by_pos,
    int* __restrict__ rowpos,
    float* __restrict__ out_loss, float* __restrict__ out_load)
{
    __shared__ int aoff[NEXP + 1];
    __shared__ int blk_cnt[NEXP];
    __shared__ int blk_base[NEXP];
    __shared__ int ired[256];
    __shared__ float fred[256];
    __shared__ float gsum[NEXP], lsum[NEXP];
    int tid = threadIdx.x;
    int e = tid & 7, g = tid >> 3;

    // every block reduces counts (needed for aoff)
    int s = 0;
    for (int k = g; k < MEGA_GATE; k += 32) s += partial_c[k * 8 + e];
    ired[tid] = s;
    if (tid < NEXP) blk_cnt[tid] = 0;
    __syncthreads();
    if (tid < 64) ired[tid] = ired[tid] + ired[tid + 64] + ired[tid + 128] + ired[tid + 192];
    __syncthreads();
    if (tid < 8) {
        int t = 0;
        for (int q = tid; q < 64; q += 8) t += ired[q];
        ired[tid] = t; // cnt per expert now in ired[0..7]
    }
    __syncthreads();
    if (tid == 0) {
        int acc = 0; aoff[0] = 0;
        for (int k = 0; k < NEXP; k++) { acc += (ired[k] + 127) & ~127; aoff[k + 1] = acc; }
    }
    __syncthreads();

    int p = blockIdx.x * 256 + tid;
    int pe = pair_expert[p];
    int local = atomicAdd(&blk_cnt[pe], 1);
    __syncthreads();
    if (tid < NEXP)
        blk_base[tid] = aoff[tid] + atomicAdd(&small[SM_CUR + tid], blk_cnt[tid]);
    if (blockIdx.x == 0 && tid < NEXP + 1) small[SM_AOFF + tid] = aoff[tid];
    __syncthreads();
    int pos = blk_base[pe] + local;
    bucket_rows[pos] = p >> 1;
    gate_by_pos[pos] = pair_gate[p];
    rowpos[p] = pos;

    if (blockIdx.x == 0) { // loss + load from partials
        float sg = 0.f, sl = 0.f;
        for (int k = g; k < MEGA_GATE; k += 32) { sg += partial_g[k * 8 + e]; sl += partial_l[k * 8 + e]; }
        fred[tid] = sg;
        __syncthreads();
        if (tid < 64) fred[tid] = fred[tid] + fred[tid + 64] + fred[tid + 128] + fred[tid + 192];
        __syncthreads();
        if (tid < 8) { float t = 0.f; for (int q = tid; q < 64; q += 8) t += fred[q]; gsum[tid] = t; }
        __syncthreads();
        fred[tid] = sl;
        __syncthreads();
        if (tid < 64) fred[tid] = fred[tid] + fred[tid + 64] + fred[tid + 128] + fred[tid + 192];
        __syncthreads();
        if (tid < 8) { float t = 0.f; for (int q = tid; q < 64; q += 8) t += fred[q]; lsum[tid] = t; }
        __syncthreads();
        if (tid == 0) {
            float cv[2];
            for (int t = 0; t < 2; t++) {
                const float* v = t ? lsum : gsum;
                float m = 0.f;
                for (int k = 0; k < NEXP; k++) m += v[k];
                m *= (1.f / NEXP);
                float var = 0.f;
                for (int k = 0; k < NEXP; k++) { float d = v[k] - m; var += d * d; }
                var *= (1.f / NEXP);
                cv[t] = var / (m * m + 1e-10f);
            }
            out_loss[0] = 0.01f * (cv[0] + cv[1]);
            int tot = 0;
            for (int k = 0; k < NEXP; k++) tot += ired[k];
            float inv = 1.f / (float)tot;
            for (int k = 0; k < NEXP; k++) out_load[k] = (float)ired[k] * inv;
        }
    }
}

// ---------------- gemmA: mode0 + mode2, R21: fat tile + 3-buffer counted-vmcnt pipeline ----------------
// 512 thr, 128x256 tile, BK32, 3 LDS buffers (72KB), 2-deep prefetch,
// ONE s_barrier/iter, s_waitcnt vmcnt(3) (never 0 in steady state) — loads
// stay in flight across barriers (T4). R12's earlier failure was the
// occupancy cost at 256-thr (3 blk -> 2 blk); here grids run ~1-2.7 blk/CU
// regardless, so only the pipeline depth changes.
// y<4:  gathered x_norm @ W1[e]^T (bn = y*256 of HDIM), +b1, SiLU -> a_buf.
// y==4: mode2 x_bf @ owT^T (blockIdx.x<128), plain fp32 stores to y.
__global__ __launch_bounds__(512) void gemmA_kernel(
    const u16* __restrict__ xnorm, const u16* __restrict__ W1b,
    const u16* __restrict__ xbf, const u16* __restrict__ owT,
    const int* __restrict__ bucket_rows, const int* __restrict__ small,
    const float* __restrict__ b1, const u16* __restrict__ zeropage,
    u16* __restrict__ a_buf, float* __restrict__ y)
{
    constexpr int KD = 512;
    __shared__ __align__(16) u16 As[3][128 * 32];
    __shared__ __align__(16) u16 Bs[3][256 * 32];

    int tid = threadIdx.x;
    int wave = tid >> 6, lane = tid & 63;
    const int lrow = lane >> 2;                              // row within 16-row chunk
    const int kcol = (((lane & 3) ^ ((lane >> 3) & 3)) * 8); // pre-swizzled global col-group
    int wm = (wave >> 2) * 64, wn = (wave & 3) * 64;         // wave -> 64x64 of 128x256
    int fr = lane & 15, kq = lane >> 4;
    const int kg = ((kq ^ ((fr >> 1) & 3)) * 8);             // swizzled read group

    bool m0 = blockIdx.y < 4;
    int base, bn, e = 0;
    const u16 *ga0, *gb0, *gb1;
    if (m0) {
        base = blockIdx.x * 128;
        if (base >= small[SM_AOFF + 8]) return;
        while (e < 7 && base >= small[SM_AOFF + e + 1]) ++e;
        bn = blockIdx.y * 256;
        int r0 = bucket_rows[base + wave * 16 + lrow];
        ga0 = ((r0 < 0) ? zeropage : xnorm + (size_t)r0 * KD) + kcol;
        const u16* Bsel = W1b + (size_t)e * HDIM * KD;
        gb0 = Bsel + (size_t)(bn + wave * 32 + lrow) * KD + kcol;
        gb1 = Bsel + (size_t)(bn + wave * 32 + 16 + lrow) * KD + kcol;
    } else {
        int j = blockIdx.x;
        if (j >= 128) return;
        base = (j >> 1) * 128;
        bn = (j & 1) * 256;
        ga0 = xbf + (size_t)(base + wave * 16 + lrow) * KD + kcol;
        gb0 = owT + (size_t)(bn + wave * 32 + lrow) * KD + kcol;
        gb1 = owT + (size_t)(bn + wave * 32 + 16 + lrow) * KD + kcol;
    }
    const int ofA = (wave * 16) * 32;
    const int ofB0 = (wave * 32) * 32;
    const int ofB1 = (wave * 32 + 16) * 32;

    float4v acc[4][4];
#pragma unroll
    for (int i = 0; i < 4; i++)
#pragma unroll
        for (int j = 0; j < 4; j++) acc[i][j] = (float4v){0.f, 0.f, 0.f, 0.f};

    constexpr int nk = KD >> 5; // 16
    // prologue: tiles 0,1 in flight (6 loads/wave)
    async_copy16(&As[0][ofA], ga0);
    async_copy16(&Bs[0][ofB0], gb0);
    async_copy16(&Bs[0][ofB1], gb1);
    async_copy16(&As[1][ofA], ga0 + 32);
    async_copy16(&Bs[1][ofB0], gb0 + 32);
    async_copy16(&Bs[1][ofB1], gb1 + 32);

    int cur = 0;
    for (int t = 0; t < nk; ++t) {
        if (t == nk - 1) asm volatile("s_waitcnt vmcnt(0)" ::: "memory");
        else             asm volatile("s_waitcnt vmcnt(3)" ::: "memory");
        __builtin_amdgcn_s_barrier();
        __builtin_amdgcn_sched_barrier(0);
        if (t + 2 < nk) { // issue tile t+2 into buffer last read at iter t-1 (safe: barrier t passed)
            int nb = cur + 2; if (nb >= 3) nb -= 3;
            int k2 = (t + 2) << 5;
            async_copy16(&As[nb][ofA], ga0 + k2);
            async_copy16(&Bs[nb][ofB0], gb0 + k2);
            async_copy16(&Bs[nb][ofB1], gb1 + k2);
        }
        short8 af[4], bf[4];
#pragma unroll
        for (int mt = 0; mt < 4; mt++) af[mt] = *(const short8*)&As[cur][(wm + mt * 16 + fr) * 32 + kg];
#pragma unroll
        for (int nt = 0; nt < 4; nt++) bf[nt] = *(const short8*)&Bs[cur][(wn + nt * 16 + fr) * 32 + kg];
#pragma unroll
        for (int mt = 0; mt < 4; mt++)
#pragma unroll
            for (int nt = 0; nt < 4; nt++)
                acc[mt][nt] = __builtin_amdgcn_mfma_f32_16x16x32_bf16(af[mt], bf[nt], acc[mt][nt], 0, 0, 0);
        cur = cur + 1; if (cur >= 3) cur = 0;
    }

    int rbase = (lane >> 4) * 4, c16 = lane & 15;
    if (m0) {
#pragma unroll
        for (int nt = 0; nt < 4; nt++) {
            int gn = bn + wn + nt * 16 + c16;
            float bv = b1[e * HDIM + gn];
#pragma unroll
            for (int mt = 0; mt < 4; mt++) {
                int gm = base + wm + mt * 16 + rbase;
#pragma unroll
                for (int r = 0; r < 4; r++) {
                    float h = acc[mt][nt][r] + bv;
                    float a = h * __builtin_amdgcn_rcpf(1.f + __expf(-h)); // fast SiLU
                    a_buf[(size_t)(gm + r) * HDIM + gn] = f2bf(a);
                }
            }
        }
    } else {
#pragma unroll
        for (int mt = 0; mt < 4; mt++) {
            int gm = base + wm + mt * 16 + rbase;
#pragma unroll
            for (int nt = 0; nt < 4; nt++) {
                int gn = bn + wn + nt * 16 + c16;
#pragma unroll
                for (int r = 0; r < 4; r++)
                    y[(size_t)(gm + r) * ODIM + gn] = acc[mt][nt][r];
            }
        }
    }
}

// ---------------- gemmB: expert down-proj, dense stores, R21 pipeline ----------------
// Same 3-buffer counted-vmcnt schedule as gemmA (this kernel runs at
// ~1.06 blocks/CU — no co-resident block hides the old vmcnt(0) drain).
__global__ __launch_bounds__(512) void gemmB_kernel(
    const u16* __restrict__ a_buf, const u16* __restrict__ W2b,
    const int* __restrict__ bucket_rows, const int* __restrict__ small,
    const float* __restrict__ b2, const float* __restrict__ gate_by_pos,
    float* __restrict__ ye)
{
    constexpr int KD = 1024;
    __shared__ __align__(16) u16 As[3][128 * 32];
    __shared__ __align__(16) u16 Bs[3][256 * 32];

    int tid = threadIdx.x;
    int wave = tid >> 6, lane = tid & 63;
    const int lrow = lane >> 2;                              // row within 16-row chunk
    const int kcol = (((lane & 3) ^ ((lane >> 3) & 3)) * 8); // pre-swizzled global col-group
    int wm = (wave >> 2) * 64, wn = (wave & 3) * 64;         // wave -> 64x64 of 128x256
    int fr = lane & 15, kq = lane >> 4;
    const int kg = ((kq ^ ((fr >> 1) & 3)) * 8);             // swizzled read group

    int base = blockIdx.x * 128;
    if (base >= small[SM_AOFF + 8]) return;
    int e = 0;
    while (e < 7 && base >= small[SM_AOFF + e + 1]) ++e;
    int bn = blockIdx.y * 256;

    const u16* ga0 = a_buf + (size_t)(base + wave * 16 + lrow) * KD + kcol;
    const u16* Bsel = W2b + (size_t)e * ODIM * KD;
    const u16* gb0 = Bsel + (size_t)(bn + wave * 32 + lrow) * KD + kcol;
    const u16* gb1 = Bsel + (size_t)(bn + wave * 32 + 16 + lrow) * KD + kcol;
    const int ofA = (wave * 16) * 32;
    const int ofB0 = (wave * 32) * 32;
    const int ofB1 = (wave * 32 + 16) * 32;

    float4v acc[4][4];
#pragma unroll
    for (int i = 0; i < 4; i++)
#pragma unroll
        for (int j = 0; j < 4; j++) acc[i][j] = (float4v){0.f, 0.f, 0.f, 0.f};

    constexpr int nk = KD >> 5; // 32
    // prologue: tiles 0,1 in flight (6 loads/wave)
    async_copy16(&As[0][ofA], ga0);
    async_copy16(&Bs[0][ofB0], gb0);
    async_copy16(&Bs[0][ofB1], gb1);
    async_copy16(&As[1][ofA], ga0 + 32);
    async_copy16(&Bs[1][ofB0], gb0 + 32);
    async_copy16(&Bs[1][ofB1], gb1 + 32);

    int cur = 0;
    for (int t = 0; t < nk; ++t) {
        if (t == nk - 1) asm volatile("s_waitcnt vmcnt(0)" ::: "memory");
        else             asm volatile("s_waitcnt vmcnt(3)" ::: "memory");
        __builtin_amdgcn_s_barrier();
        __builtin_amdgcn_sched_barrier(0);
        if (t + 2 < nk) {
            int nb = cur + 2; if (nb >= 3) nb -= 3;
            int k2 = (t + 2) << 5;
            async_copy16(&As[nb][ofA], ga0 + k2);
            async_copy16(&Bs[nb][ofB0], gb0 + k2);
            async_copy16(&Bs[nb][ofB1], gb1 + k2);
        }
        short8 af[4], bf[4];
#pragma unroll
        for (int mt = 0; mt < 4; mt++) af[mt] = *(const short8*)&As[cur][(wm + mt * 16 + fr) * 32 + kg];
#pragma unroll
        for (int nt = 0; nt < 4; nt++) bf[nt] = *(const short8*)&Bs[cur][(wn + nt * 16 + fr) * 32 + kg];
#pragma unroll
        for (int mt = 0; mt < 4; mt++)
#pragma unroll
            for (int nt = 0; nt < 4; nt++)
                acc[mt][nt] = __builtin_amdgcn_mfma_f32_16x16x32_bf16(af[mt], bf[nt], acc[mt][nt], 0, 0, 0);
        cur = cur + 1; if (cur >= 3) cur = 0;
    }

    int rbase = (lane >> 4) * 4, c16 = lane & 15;
#pragma unroll
    for (int mt = 0; mt < 4; mt++) {
        int pos0 = base + wm + mt * 16 + rbase;
        int rows[4]; float gs[4];
#pragma unroll
        for (int r = 0; r < 4; r++) { rows[r] = bucket_rows[pos0 + r]; gs[r] = gate_by_pos[pos0 + r]; }
#pragma unroll
        for (int nt = 0; nt < 4; nt++) {
            int gn = bn + wn + nt * 16 + c16;
            float b2v = b2[e * ODIM + gn];
#pragma unroll
            for (int r = 0; r < 4; r++) {
                if (rows[r] >= 0)
                    ye[(size_t)(pos0 + r) * ODIM + gn] = gs[r] * (acc[mt][nt][r] + b2v);
            }
        }
    }
}

// ---------------- combine: y[row] = y_mode2[row] + ye[pos0] + ye[pos1] ----------------
__global__ __launch_bounds__(256) void combine_kernel(
    const float* __restrict__ ye, const int* __restrict__ rowpos,
    float* __restrict__ y)
{
    int tid = threadIdx.x;
    int row = blockIdx.x * 16 + (tid >> 4);
    int c0 = (tid & 15) * 32;
    int p0 = rowpos[row * 2];
    int p1 = rowpos[row * 2 + 1];
    const float4* e0 = (const float4*)(ye + (size_t)p0 * ODIM + c0);
    const float4* e1 = (const float4*)(ye + (size_t)p1 * ODIM + c0);
    float4* yp = (float4*)(y + (size_t)row * ODIM + c0);
#pragma unroll
    for (int i = 0; i < 8; i++) {
        float4 a = yp[i], b = e0[i], c = e1[i];
        a.x += b.x + c.x; a.y += b.y + c.y; a.z += b.z + c.z; a.w += b.w + c.w;
        yp[i] = a;
    }
}

extern "C" void kernel_launch(void* const* d_in, const int* in_sizes, int n_in,
                              void* d_out, int out_size, void* d_ws, size_t ws_size,
                              hipStream_t stream)
{
    (void)in_sizes; (void)n_in; (void)out_size; (void)ws_size;
    const float* x = (const float*)d_in[0];
    // d_in[1] x_offsets, d_in[2] max_seq_len: unused by the reference math
    const float* noise = (const float*)d_in[3];
    const float* norm_w = (const float*)d_in[4];
    const float* norm_b = (const float*)d_in[5];
    const float* w_gate = (const float*)d_in[6];
    const float* w_noise = (const float*)d_in[7];
    const float* W1 = (const float*)d_in[8];
    const float* b1 = (const float*)d_in[9];
    const float* W2 = (const float*)d_in[10];
    const float* b2 = (const float*)d_in[11];
    const float* ow = (const float*)d_in[12];

    float* y = (float*)d_out;
    float* out_loss = y + (size_t)N_ROWS * ODIM;
    float* out_load = out_loss + 1;

    char* ws = (char*)d_ws;
    size_t off = 0;
    auto alloc = [&](size_t b) { size_t p = off; off = (off + b + 255) & ~(size_t)255; return p; };
    u16* xnorm_bf = (u16*)(ws + alloc((size_t)N_ROWS * DDIM * 2));
    u16* x_bf     = (u16*)(ws + alloc((size_t)N_ROWS * DDIM * 2));
    u16* W1b      = (u16*)(ws + alloc((size_t)NEXP * HDIM * DDIM * 2));
    u16* W2b      = (u16*)(ws + alloc((size_t)NEXP * ODIM * HDIM * 2));
    u16* owT      = (u16*)(ws + alloc((size_t)DDIM * ODIM * 2));
    u16* a_buf    = (u16*)(ws + alloc((size_t)MAXPOS * HDIM * 2));
    float* ye     = (float*)(ws + alloc((size_t)MAXPOS * ODIM * 4));
    int* pair_expert = (int*)(ws + alloc((size_t)MAXPAIRS * 4));
    float* pair_gate = (float*)(ws + alloc((size_t)MAXPAIRS * 4));
    float* gate_by_pos = (float*)(ws + alloc((size_t)MAXPOS * 4));
    int* bucket_rows = (int*)(ws + alloc((size_t)MAXPOS * 4));
    int* rowpos      = (int*)(ws + alloc((size_t)MAXPAIRS * 4));
    int* small       = (int*)(ws + alloc(SM_WORDS * 4));
    float* zeropage  = (float*)(ws + alloc(2048));
    float* partial_g = (float*)(ws + alloc((size_t)MEGA_GATE * NEXP * 4));
    float* partial_l = (float*)(ws + alloc((size_t)MEGA_GATE * NEXP * 4));
    int* partial_c   = (int*)(ws + alloc((size_t)MEGA_GATE * NEXP * 4));

    mega_kernel<<<MEGA_BLOCKS, 256, 0, stream>>>(
        x, noise, norm_w, norm_b, w_gate, w_noise, W1, ow, W2,
        xnorm_bf, x_bf, pair_expert, pair_gate, W1b, owT, W2b,
        bucket_rows, small, zeropage, partial_g, partial_l, partial_c);
    scatter_kernel<<<MAXPAIRS / 256, 256, 0, stream>>>(pair_expert, pair_gate,
                                                       partial_g, partial_l, partial_c,
                                                       small, bucket_rows, gate_by_pos, rowpos,
                                                       out_loss, out_load);
    gemmA_kernel<<<dim3(MAXTILES, 5), 512, 0, stream>>>(xnorm_bf, W1b,
                                                        x_bf, owT, bucket_rows, small, b1,
                                                        (const u16*)zeropage, a_buf, y);
    gemmB_kernel<<<dim3(MAXTILES, 2), 512, 0, stream>>>(a_buf, W2b, bucket_rows,
                                                        small, b2, gate_by_pos, ye);
    combine_kernel<<<N_ROWS / 16, 256, 0, stream>>>(ye, rowpos, y);
}